// Round 11
// baseline (207.085 us; speedup 1.0000x reference)
//
#include <hip/hip_runtime.h>
#include <cstddef>
#include <cstdint>

typedef unsigned short ushort_t;
typedef short short8 __attribute__((ext_vector_type(8)));
typedef float f32x4 __attribute__((ext_vector_type(4)));

#define BB 16
#define CC 256
#define CI 128
#define NN 2048
#define BN_EPS 1e-5f
#define NCH 4      // split-N chunks for Gram

// ---------------- workspace layout (float offsets, all 16B-aligned) -------
#define OFF_EH    0u          // 256x128 bf16 = 16384 fl
#define OFF_WGT   16384u      // 256x128 bf16 (W_g^T)
#define OFF_WFT   32768u      // 256x128 bf16 (W_phi^T)
#define OFF_WTT   49152u      // 256x128 bf16 (W_theta^T)
#define OFF_LH    65536u      // 256x256 bf16 = 32768 fl
#define OFF_RT    98304u      // 256x256 bf16 (R^T)
#define OFF_Q     131072u     // 256 f32
#define OFF_W1    131328u
#define OFF_EG    131584u
#define OFF_BB2   131840u
#define OFF_BFBT  132096u     // 16 fl
#define OFF_S     132112u     // 16x256 f32 = 4096
#define OFF_V1    136208u     // 16x256
#define OFF_V2    140304u     // 16x256
#define OFF_SQ    144400u     // 16
#define OFF_BIASP 144416u     // 16x256
#define OFF_GH    148512u     // 16x65536 bf16 = 524288 fl
#define OFF_TH    672800u     // 16x65536 bf16
#define OFF_PH    1197088u    // 16x65536 bf16
#define OFF_XH    1721376u    // 16x256x2048 bf16 = 4194304 fl
#define OFF_XHT   5915680u    // 16x2048x256 bf16 = 4194304 fl
#define OFF_GP    10109984u   // 4x16x65536 f32 = 4194304 fl
#define WS_FLOATS 14304288u   // ~57.2 MB

__device__ __forceinline__ ushort_t f2bf(float f) {
  unsigned int u = __float_as_uint(f);
  u += 0x7fffu + ((u >> 16) & 1u);
  return (ushort_t)(u >> 16);
}
__device__ __forceinline__ float bf2f(ushort_t h) {
  return __uint_as_float((unsigned int)h << 16);
}

__device__ __forceinline__ void gl_lds16(const void* gsrc, void* ldst) {
  __builtin_amdgcn_global_load_lds(
      (const __attribute__((address_space(1))) void*)gsrc,
      (__attribute__((address_space(3))) void*)ldst, 16, 0, 0);
}

// ---------------------------------------------------------------------------
// Proven MFMA core (validated R9, absmax 0.031): C[128x128], 4 waves, BK=64.
// NT-gemm: A rows (M,K-contig), B rows (N,K-contig). Both-sides ^(row&7)
// granule swizzle; global_load_lds w=16; lds linear dest.
// ---------------------------------------------------------------------------
__device__ __forceinline__ void mfma_core(
    const ushort_t* gA, size_t ldA, const ushort_t* gB, size_t ldB,
    int kIters, ushort_t* ldsA, ushort_t* ldsB, f32x4 acc[4][4]) {
  const int t = threadIdx.x;
  const int wave = t >> 6, lane = t & 63;
  const int wm = wave & 1, wn = wave >> 1;
  const int l15 = lane & 15, lhi = lane >> 4;

  for (int kt = 0; kt < kIters; ++kt) {
#pragma unroll
    for (int q = 0; q < 4; ++q) {
      int row = wave * 32 + q * 8 + (lane >> 3);
      int gs = (lane & 7) ^ (row & 7);
      gl_lds16(gA + (size_t)row * ldA + gs * 8, &ldsA[(wave * 4 + q) * 512]);
    }
#pragma unroll
    for (int q = 0; q < 4; ++q) {
      int row = wave * 32 + q * 8 + (lane >> 3);
      int gs = (lane & 7) ^ (row & 7);
      gl_lds16(gB + (size_t)row * ldB + gs * 8, &ldsB[(wave * 4 + q) * 512]);
    }
    __syncthreads();
#pragma unroll
    for (int ks = 0; ks < 2; ++ks) {
      short8 af[4], bf[4];
#pragma unroll
      for (int i = 0; i < 4; ++i) {
        int rowA = wm * 64 + i * 16 + l15;
        int grA = (4 * ks + lhi) ^ (rowA & 7);
        af[i] = *(const short8*)&ldsA[rowA * 64 + grA * 8];
        int rowB = wn * 64 + i * 16 + l15;
        int grB = (4 * ks + lhi) ^ (rowB & 7);
        bf[i] = *(const short8*)&ldsB[rowB * 64 + grB * 8];
      }
#pragma unroll
      for (int i = 0; i < 4; ++i)
#pragma unroll
        for (int j = 0; j < 4; ++j)
          acc[i][j] = __builtin_amdgcn_mfma_f32_16x16x32_bf16(
              af[i], bf[j], acc[i][j], 0, 0, 0);
    }
    __syncthreads();
    gA += 64; gB += 64;
  }
}

#define ACC_INIT(acc) \
  _Pragma("unroll") for (int i_ = 0; i_ < 4; ++i_) \
  _Pragma("unroll") for (int j_ = 0; j_ < 4; ++j_) \
  _Pragma("unroll") for (int e_ = 0; e_ < 4; ++e_) acc[i_][j_][e_] = 0.f;

// D[a][b]: a = m0+wm*64+i*16+4*lhi+r (A side), b = n0+wn*64+j*16+l15 (B side)
__device__ __forceinline__ void store_bf16_D(
    f32x4 acc[4][4], ushort_t* D, int ldd, int m0, int n0) {
  int t = threadIdx.x, wave = t >> 6, lane = t & 63;
  int wm = wave & 1, wn = wave >> 1, l15 = lane & 15, lhi = lane >> 4;
#pragma unroll
  for (int i = 0; i < 4; ++i)
#pragma unroll
    for (int j = 0; j < 4; ++j)
#pragma unroll
      for (int r = 0; r < 4; ++r) {
        int a = m0 + wm * 64 + i * 16 + 4 * lhi + r;
        int bc = n0 + wn * 64 + j * 16 + l15;
        D[(size_t)a * ldd + bc] = f2bf(acc[i][j][r]);
      }
}

// ---------------------------------------------------------------------------
// pack: E_h = (inv/N)*w_out [256][128]; WgT/WfT/WtT transposes bf16; bias2
// ---------------------------------------------------------------------------
__global__ __launch_bounds__(256) void pack(
    const float* __restrict__ wg, const float* __restrict__ wp,
    const float* __restrict__ wt, const float* __restrict__ wout,
    const float* __restrict__ gamma, const float* __restrict__ run_var,
    const float* __restrict__ b_out, const float* __restrict__ beta,
    const float* __restrict__ run_mean,
    ushort_t* __restrict__ Eh, ushort_t* __restrict__ WgT,
    ushort_t* __restrict__ WfT, ushort_t* __restrict__ WtT,
    float* __restrict__ bias2) {
  int gid = blockIdx.x * 256 + threadIdx.x;
  if (gid < 4 * 32768) {
    int which = gid >> 15, idx = gid & 32767;
    int c = idx >> 7, j = idx & 127;
    if (which == 0) {
      float inv = gamma[c] * rsqrtf(run_var[c] + BN_EPS);
      Eh[idx] = f2bf(inv * (1.0f / (float)NN) * wout[idx]);
    } else {
      const float* src = (which == 1) ? wg : (which == 2) ? wp : wt;
      ushort_t* dst = (which == 1) ? WgT : (which == 2) ? WfT : WtT;
      dst[idx] = f2bf(src[(size_t)j * CC + c]);
    }
  } else if (gid < 4 * 32768 + CC) {
    int o = gid - 4 * 32768;
    float inv = gamma[o] * rsqrtf(run_var[o] + BN_EPS);
    bias2[o] = b_out[o] * inv + beta[o] - run_mean[o] * inv;
  }
}

// pack2: q = Wphi^T b_theta; w1 = Wtheta^T b_phi; e_g = (inv/N)(w_out b_g); bfbt
__global__ __launch_bounds__(256) void pack2(
    const float* __restrict__ wp, const float* __restrict__ wt,
    const float* __restrict__ wout, const float* __restrict__ bt,
    const float* __restrict__ bp, const float* __restrict__ bg,
    const float* __restrict__ gamma, const float* __restrict__ run_var,
    float* __restrict__ q, float* __restrict__ w1, float* __restrict__ eg,
    float* __restrict__ bfbt) {
  int t = threadIdx.x;
  float aq = 0.f, aw = 0.f;
  for (int j = 0; j < CI; ++j) {
    aq += wp[(size_t)j * CC + t] * bt[j];
    aw += wt[(size_t)j * CC + t] * bp[j];
  }
  q[t] = aq; w1[t] = aw;
  float inv = gamma[t] * rsqrtf(run_var[t] + BN_EPS);
  float s2 = 0.f;
  for (int i = 0; i < CI; ++i) s2 += wout[(size_t)t * CI + i] * bg[i];
  eg[t] = inv * (1.0f / (float)NN) * s2;
  if (t == 0) {
    float d = 0.f;
    for (int j = 0; j < CI; ++j) d += bp[j] * bt[j];
    *bfbt = d;
  }
}

// ---------------------------------------------------------------------------
// cast_x: x f32 -> xhT[b][n][c] bf16 (transposed) + xh[b][c][n] bf16 + row sums s
// ---------------------------------------------------------------------------
__global__ __launch_bounds__(256) void cast_x(
    const float* __restrict__ x, ushort_t* __restrict__ xhT,
    ushort_t* __restrict__ xh, float* __restrict__ s) {
  __shared__ float Xs[64][65];
  int n0 = blockIdx.x * 64, c0 = blockIdx.y * 64, b = blockIdx.z;
  int t = threadIdx.x;
  int tr = t >> 4, tc = (t & 15) * 4;
#pragma unroll
  for (int p = 0; p < 4; ++p) {
    int row = p * 16 + tr;
    float4 v = *(const float4*)&x[((size_t)b * CC + c0 + row) * NN + n0 + tc];
    Xs[row][tc] = v.x; Xs[row][tc + 1] = v.y; Xs[row][tc + 2] = v.z; Xs[row][tc + 3] = v.w;
  }
  __syncthreads();
#pragma unroll
  for (int p = 0; p < 4; ++p) {  // xhT (transposed)
    int j = p * 16 + tr;
    ushort4 hv;
    hv.x = f2bf(Xs[tc][j]); hv.y = f2bf(Xs[tc + 1][j]);
    hv.z = f2bf(Xs[tc + 2][j]); hv.w = f2bf(Xs[tc + 3][j]);
    *(ushort4*)&xhT[((size_t)b * NN + n0 + j) * CC + c0 + tc] = hv;
  }
  {  // xh (plain cast)
    int row = t >> 2, cg = (t & 3) * 16;
    size_t base = ((size_t)b * CC + c0 + row) * NN + n0 + cg;
#pragma unroll
    for (int e = 0; e < 4; ++e) {
      ushort4 hv;
      hv.x = f2bf(Xs[row][cg + 4 * e]);     hv.y = f2bf(Xs[row][cg + 4 * e + 1]);
      hv.z = f2bf(Xs[row][cg + 4 * e + 2]); hv.w = f2bf(Xs[row][cg + 4 * e + 3]);
      *(ushort4*)&xh[base + 4 * e] = hv;
    }
  }
  if (t < 64) {  // partial row sums
    float p = 0.f;
    for (int j2 = 0; j2 < 64; ++j2) p += Xs[t][j2];
    atomicAdd(&s[(size_t)b * CC + c0 + t], p);
  }
}

// gemm_k128: D[256][256] = A[256][128] x B[256][128]^T (NT), bf16 out
__global__ __launch_bounds__(256) void gemm_k128(
    const ushort_t* __restrict__ A, const ushort_t* __restrict__ B,
    ushort_t* __restrict__ D) {
  __shared__ __align__(16) ushort_t As[8192], Bs[8192];
  int n0 = blockIdx.x * 128, m0 = blockIdx.y * 128;
  f32x4 acc[4][4]; ACC_INIT(acc);
  mfma_core(A + (size_t)m0 * 128, 128, B + (size_t)n0 * 128, 128, 2, As, Bs, acc);
  store_bf16_D(acc, D, CC, m0, n0);
}

// k_G: G_part[ch][b] = xh[i-rows] . xh[j-rows]^T over n-chunk (f32 out)
__global__ __launch_bounds__(256) void k_G(
    const ushort_t* __restrict__ xh, float* __restrict__ G_part) {
  __shared__ __align__(16) ushort_t As[8192], Bs[8192];
  int ch = blockIdx.x, ij = blockIdx.y, b = blockIdx.z;
  int ti = ij >> 1, tj = ij & 1;
  f32x4 acc[4][4]; ACC_INIT(acc);
  mfma_core(xh + ((size_t)b * CC + ti * 128) * NN + ch * (NN / NCH), NN,
            xh + ((size_t)b * CC + tj * 128) * NN + ch * (NN / NCH), NN,
            (NN / NCH) / 64, As, Bs, acc);
  float* dst = G_part + ((size_t)ch * BB + b) * (CC * CC);
  int t = threadIdx.x, wave = t >> 6, lane = t & 63;
  int wm = wave & 1, wn = wave >> 1, l15 = lane & 15, lhi = lane >> 4;
#pragma unroll
  for (int i = 0; i < 4; ++i)
#pragma unroll
    for (int j = 0; j < 4; ++j)
#pragma unroll
      for (int r = 0; r < 4; ++r) {
        int a = ti * 128 + wm * 64 + i * 16 + 4 * lhi + r;
        int bc = tj * 128 + wn * 64 + j * 16 + l15;
        dst[(size_t)a * CC + bc] = acc[i][j][r];
      }
}

// g_red: Gh = bf16(sum_ch G_part)
__global__ __launch_bounds__(256) void g_red(
    const float* __restrict__ G_part, ushort_t* __restrict__ Gh) {
  int b = blockIdx.y;
  int e = blockIdx.x * 256 + threadIdx.x;
  float v = 0.f;
#pragma unroll
  for (int c = 0; c < NCH; ++c)
    v += G_part[((size_t)c * BB + b) * (CC * CC) + e];
  Gh[(size_t)b * (CC * CC) + e] = f2bf(v);
}

// k_s: v1 = L s; v2 = Rt s; sq = s.q   (per batch)
__global__ __launch_bounds__(256) void k_s(
    const ushort_t* __restrict__ Lh, const ushort_t* __restrict__ Rt,
    const float* __restrict__ s, const float* __restrict__ q,
    float* __restrict__ v1, float* __restrict__ v2, float* __restrict__ sq) {
  __shared__ float sl[256], red[256];
  int b = blockIdx.x, t = threadIdx.x;
  sl[t] = s[(size_t)b * CC + t];
  __syncthreads();
  float a1 = 0.f, a2 = 0.f;
  for (int c = 0; c < CC; ++c) {
    a1 += bf2f(Lh[(size_t)t * CC + c]) * sl[c];
    a2 += bf2f(Rt[(size_t)t * CC + c]) * sl[c];
  }
  v1[(size_t)b * CC + t] = a1;
  v2[(size_t)b * CC + t] = a2;
  red[t] = sl[t] * q[t];
  __syncthreads();
  for (int st = 128; st > 0; st >>= 1) {
    if (t < st) red[t] += red[t + st];
    __syncthreads();
  }
  if (t == 0) sq[b] = red[0];
}

// c1: T = L . G (per b), bf16
__global__ __launch_bounds__(256) void c1(
    const ushort_t* __restrict__ Lh, const ushort_t* __restrict__ Gh,
    ushort_t* __restrict__ Th) {
  __shared__ __align__(16) ushort_t As[8192], Bs[8192];
  int n0 = blockIdx.x * 128, m0 = blockIdx.y * 128, b = blockIdx.z;
  f32x4 acc[4][4]; ACC_INIT(acc);
  mfma_core(Lh + (size_t)m0 * CC, CC,
            Gh + (size_t)b * (CC * CC) + (size_t)n0 * CC, CC, 4, As, Bs, acc);
  store_bf16_D(acc, Th + (size_t)b * (CC * CC), CC, m0, n0);
}

// c2: P = T . R + rank-2 bias terms (per b), bf16
__global__ __launch_bounds__(256) void c2(
    const ushort_t* __restrict__ Th, const ushort_t* __restrict__ Rt,
    const float* __restrict__ v1, const float* __restrict__ v2,
    const float* __restrict__ eg, const float* __restrict__ w1,
    ushort_t* __restrict__ Ph) {
  __shared__ __align__(16) ushort_t As[8192], Bs[8192];
  int n0 = blockIdx.x * 128, m0 = blockIdx.y * 128, b = blockIdx.z;
  f32x4 acc[4][4]; ACC_INIT(acc);
  mfma_core(Th + (size_t)b * (CC * CC) + (size_t)m0 * CC, CC,
            Rt + (size_t)n0 * CC, CC, 4, As, Bs, acc);
  ushort_t* D = Ph + (size_t)b * (CC * CC);
  int t = threadIdx.x, wave = t >> 6, lane = t & 63;
  int wm = wave & 1, wn = wave >> 1, l15 = lane & 15, lhi = lane >> 4;
#pragma unroll
  for (int i = 0; i < 4; ++i)
#pragma unroll
    for (int r = 0; r < 4; ++r) {
      int o = m0 + wm * 64 + i * 16 + 4 * lhi + r;
      float vo = v1[(size_t)b * CC + o] + (float)NN * eg[o];
      float eo = eg[o];
#pragma unroll
      for (int j = 0; j < 4; ++j) {
        int c = n0 + wn * 64 + j * 16 + l15;
        float val = acc[i][j][r] + eo * v2[(size_t)b * CC + c] + vo * w1[c];
        D[(size_t)o * CC + c] = f2bf(val);
      }
    }
}

// k_bias: bias'[b][o] = T q + eg*sq + (v1+N*eg)*bfbt + bias2
__global__ __launch_bounds__(256) void k_bias(
    const ushort_t* __restrict__ Th, const float* __restrict__ q,
    const float* __restrict__ eg, const float* __restrict__ v1,
    const float* __restrict__ sq, const float* __restrict__ bfbt,
    const float* __restrict__ bias2, float* __restrict__ biasp) {
  int b = blockIdx.x, o = threadIdx.x;
  const ushort_t* Trow = Th + (size_t)b * (CC * CC) + (size_t)o * CC;
  float a = 0.f;
  for (int k = 0; k < CC; ++k) a += bf2f(Trow[k]) * q[k];
  biasp[(size_t)b * CC + o] =
      a + eg[o] * sq[b] + (v1[(size_t)b * CC + o] + (float)NN * eg[o]) * (*bfbt)
      + bias2[o];
}

// k_out: out = P . x + bias' + x  (A = P rows, B = xhT rows)
__global__ __launch_bounds__(256) void k_out(
    const ushort_t* __restrict__ Ph, const ushort_t* __restrict__ xhT,
    const float* __restrict__ biasp, const float* __restrict__ x,
    float* __restrict__ out) {
  __shared__ __align__(16) ushort_t As[8192], Bs[8192];
  int n0 = blockIdx.x * 128, o0 = blockIdx.y * 128, b = blockIdx.z;
  f32x4 acc[4][4]; ACC_INIT(acc);
  mfma_core(Ph + (size_t)b * (CC * CC) + (size_t)o0 * CC, CC,
            xhT + ((size_t)b * NN + n0) * CC, CC, 4, As, Bs, acc);
  int t = threadIdx.x, wave = t >> 6, lane = t & 63;
  int wm = wave & 1, wn = wave >> 1, l15 = lane & 15, lhi = lane >> 4;
#pragma unroll
  for (int i = 0; i < 4; ++i)
#pragma unroll
    for (int r = 0; r < 4; ++r) {
      int o = o0 + wm * 64 + i * 16 + 4 * lhi + r;
      float bo = biasp[(size_t)b * CC + o];
#pragma unroll
      for (int j = 0; j < 4; ++j) {
        int n = n0 + wn * 64 + j * 16 + l15;
        size_t idx = ((size_t)b * CC + o) * NN + n;
        out[idx] = acc[i][j][r] + bo + x[idx];
      }
    }
}

// ---------------------------------------------------------------------------
extern "C" void kernel_launch(void* const* d_in, const int* in_sizes, int n_in,
                              void* d_out, int out_size, void* d_ws, size_t ws_size,
                              hipStream_t stream) {
  const float* x        = (const float*)d_in[0];
  const float* w_theta  = (const float*)d_in[1];
  const float* b_theta  = (const float*)d_in[2];
  const float* w_phi    = (const float*)d_in[3];
  const float* b_phi    = (const float*)d_in[4];
  const float* w_g      = (const float*)d_in[5];
  const float* b_g      = (const float*)d_in[6];
  const float* w_out    = (const float*)d_in[7];
  const float* b_out    = (const float*)d_in[8];
  const float* gamma    = (const float*)d_in[9];
  const float* beta     = (const float*)d_in[10];
  const float* run_mean = (const float*)d_in[11];
  const float* run_var  = (const float*)d_in[12];
  float* out = (float*)d_out;
  float* ws  = (float*)d_ws;

  if (ws_size < (size_t)WS_FLOATS * sizeof(float)) return;

  ushort_t* Eh   = (ushort_t*)(ws + OFF_EH);
  ushort_t* WgT  = (ushort_t*)(ws + OFF_WGT);
  ushort_t* WfT  = (ushort_t*)(ws + OFF_WFT);
  ushort_t* WtT  = (ushort_t*)(ws + OFF_WTT);
  ushort_t* Lh   = (ushort_t*)(ws + OFF_LH);
  ushort_t* Rt   = (ushort_t*)(ws + OFF_RT);
  float*    q    = ws + OFF_Q;
  float*    w1   = ws + OFF_W1;
  float*    eg   = ws + OFF_EG;
  float*    bias2= ws + OFF_BB2;
  float*    bfbt = ws + OFF_BFBT;
  float*    s    = ws + OFF_S;
  float*    v1   = ws + OFF_V1;
  float*    v2   = ws + OFF_V2;
  float*    sq   = ws + OFF_SQ;
  float*    biasp= ws + OFF_BIASP;
  ushort_t* Gh   = (ushort_t*)(ws + OFF_GH);
  ushort_t* Th   = (ushort_t*)(ws + OFF_TH);
  ushort_t* Ph   = (ushort_t*)(ws + OFF_PH);
  ushort_t* xh   = (ushort_t*)(ws + OFF_XH);
  ushort_t* xhT  = (ushort_t*)(ws + OFF_XHT);
  float*    Gp   = ws + OFF_GP;

  pack<<<dim3(513), 256, 0, stream>>>(w_g, w_phi, w_theta, w_out, gamma, run_var,
                                      b_out, beta, run_mean, Eh, WgT, WfT, WtT, bias2);
  pack2<<<dim3(1), 256, 0, stream>>>(w_phi, w_theta, w_out, b_theta, b_phi, b_g,
                                     gamma, run_var, q, w1, eg, bfbt);
  hipMemsetAsync(s, 0, (size_t)BB * CC * sizeof(float), stream);
  cast_x<<<dim3(NN / 64, CC / 64, BB), 256, 0, stream>>>(x, xhT, xh, s);
  gemm_k128<<<dim3(2, 2), 256, 0, stream>>>(Eh, WgT, Lh);    // L = E Wg
  gemm_k128<<<dim3(2, 2), 256, 0, stream>>>(WtT, WfT, Rt);   // Rt = R^T
  k_G<<<dim3(NCH, 4, BB), 256, 0, stream>>>(xh, Gp);
  g_red<<<dim3(CC * CC / 256, BB), 256, 0, stream>>>(Gp, Gh);
  k_s<<<dim3(BB), 256, 0, stream>>>(Lh, Rt, s, q, v1, v2, sq);
  c1<<<dim3(2, 2, BB), 256, 0, stream>>>(Lh, Gh, Th);
  c2<<<dim3(2, 2, BB), 256, 0, stream>>>(Th, Rt, v1, v2, eg, w1, Ph);
  k_bias<<<dim3(BB), 256, 0, stream>>>(Th, q, eg, v1, sq, bfbt, bias2, biasp);
  k_out<<<dim3(NN / 128, CC / 128, BB), 256, 0, stream>>>(Ph, xhT, biasp, x, out);
}